// Round 1
// baseline (113.398 us; speedup 1.0000x reference)
//
#include <hip/hip_runtime.h>
#include <hip/hip_bf16.h>
#include <math.h>

#define B_ 8192
#define P_ 24
#define Q_ 12
#define E_ 256
#define V_ 1000
#define TOK_ 36
#define NK_ 129      // knots
#define NI_ 128      // intervals
#define KT_ 16       // knots per build block
#define X0_ (-6.0f)
#define DX_ (12.0f / 128.0f)
#define INVDX_ (128.0f / 12.0f)
#define LN_EPS_ 1e-5f

__device__ __forceinline__ float gelu_exact(float u) {
    return 0.5f * u * (1.0f + erff(u * 0.70710678118654752f));
}

// Build table T[p][k][f] = F_p(x_k)[f] = sum_e gelu(x_k*W1[p,e]+b1[p,e]) * W2[p,e,f] + b2[p,f]
__global__ __launch_bounds__(256) void build_table(
        const float* __restrict__ W1, const float* __restrict__ b1,
        const float* __restrict__ W2, const float* __restrict__ b2,
        float* __restrict__ T) {
    int p = blockIdx.x;
    int k0 = blockIdx.y * KT_;
    int f = threadIdx.x;

    __shared__ float h[KT_][E_ + 4];   // +4 pad keeps float4 rows 16B aligned, breaks stride

    float w = W1[p * E_ + f];
    float b1v = b1[p * E_ + f];
    #pragma unroll
    for (int k = 0; k < KT_; ++k) {
        float x = X0_ + (float)(k0 + k) * DX_;
        h[k][f] = gelu_exact(fmaf(x, w, b1v));
    }
    __syncthreads();

    float acc[KT_];
    float b2v = b2[p * E_ + f];
    #pragma unroll
    for (int k = 0; k < KT_; ++k) acc[k] = b2v;

    const float* W2p = W2 + (size_t)p * E_ * E_ + f;
    for (int e = 0; e < E_; e += 4) {
        float w0 = W2p[(size_t)(e + 0) * E_];
        float w1 = W2p[(size_t)(e + 1) * E_];
        float w2v = W2p[(size_t)(e + 2) * E_];
        float w3 = W2p[(size_t)(e + 3) * E_];
        #pragma unroll
        for (int k = 0; k < KT_; ++k) {
            float4 hv = *(const float4*)&h[k][e];
            acc[k] = fmaf(hv.x, w0, acc[k]);
            acc[k] = fmaf(hv.y, w1, acc[k]);
            acc[k] = fmaf(hv.z, w2v, acc[k]);
            acc[k] = fmaf(hv.w, w3, acc[k]);
        }
    }
    #pragma unroll
    for (int k = 0; k < KT_; ++k) {
        int kk = k0 + k;
        if (kk < NK_) T[((size_t)p * NK_ + kk) * E_ + f] = acc[k];
    }
}

// Per-wave LayerNorm over 256 elems (each lane holds 4) + store
__device__ __forceinline__ void ln_store(float4 v, int lane, int e0, int row,
                                         const float* __restrict__ gamma,
                                         const float* __restrict__ beta,
                                         float* __restrict__ out) {
    float s1 = v.x + v.y + v.z + v.w;
    #pragma unroll
    for (int m = 1; m < 64; m <<= 1) s1 += __shfl_xor(s1, m, 64);
    float mean = s1 * (1.0f / (float)E_);
    float dx = v.x - mean, dy = v.y - mean, dz = v.z - mean, dw = v.w - mean;
    float s2 = dx * dx + dy * dy + dz * dz + dw * dw;
    #pragma unroll
    for (int m = 1; m < 64; m <<= 1) s2 += __shfl_xor(s2, m, 64);
    float rstd = rsqrtf(s2 * (1.0f / (float)E_) + LN_EPS_);
    float4 g = *(const float4*)&gamma[e0];
    float4 bt = *(const float4*)&beta[e0];
    float4 o;
    o.x = fmaf(dx * rstd, g.x, bt.x);
    o.y = fmaf(dy * rstd, g.y, bt.y);
    o.z = fmaf(dz * rstd, g.z, bt.z);
    o.w = fmaf(dw * rstd, g.w, bt.w);
    *(float4*)&out[(size_t)row * E_ + e0] = o;
}

// Main fused kernel: one wave per output row (token), 4 rows per block.
__global__ __launch_bounds__(256) void fuse_ln(
        const float* __restrict__ T,
        const float* __restrict__ x_num, const int* __restrict__ x_cat,
        const float* __restrict__ emb,
        const float* __restrict__ gamma, const float* __restrict__ beta,
        float* __restrict__ out) {
    int wv = threadIdx.x >> 6;
    int lane = threadIdx.x & 63;
    int row = blockIdx.x * 4 + wv;
    if (row >= B_ * TOK_) return;
    int b = row / TOK_;
    int t = row - b * TOK_;
    int e0 = lane * 4;
    float4 v;
    if (t < P_) {
        float x = x_num[b * P_ + t];
        float s = (x - X0_) * INVDX_;
        float fi = floorf(s);
        fi = fminf(fmaxf(fi, 0.0f), (float)(NI_ - 1));
        float tt = s - fi;               // may be <0 or >1 out of range -> linear extrapolation
        int i = (int)fi;
        const float* base = T + ((size_t)t * NK_ + i) * E_ + e0;
        float4 a = *(const float4*)base;
        float4 c = *(const float4*)(base + E_);
        v.x = fmaf(tt, c.x - a.x, a.x);
        v.y = fmaf(tt, c.y - a.y, a.y);
        v.z = fmaf(tt, c.z - a.z, a.z);
        v.w = fmaf(tt, c.w - a.w, a.w);
    } else {
        int q = t - P_;
        int idx = x_cat[b * Q_ + q];
        v = *(const float4*)&emb[((size_t)q * V_ + idx) * E_ + e0];
    }
    ln_store(v, lane, e0, row, gamma, beta, out);
}

// Exact fallback (no workspace): direct per-row matvec. Slow but correct.
__global__ __launch_bounds__(256) void fuse_exact(
        const float* __restrict__ x_num, const int* __restrict__ x_cat,
        const float* __restrict__ W1, const float* __restrict__ b1,
        const float* __restrict__ W2, const float* __restrict__ b2,
        const float* __restrict__ emb,
        const float* __restrict__ gamma, const float* __restrict__ beta,
        float* __restrict__ out) {
    int wv = threadIdx.x >> 6;
    int lane = threadIdx.x & 63;
    int row = blockIdx.x * 4 + wv;
    if (row >= B_ * TOK_) return;
    int b = row / TOK_;
    int t = row - b * TOK_;
    int e0 = lane * 4;
    float4 v;
    if (t < P_) {
        float x = x_num[b * P_ + t];
        float4 acc = *(const float4*)&b2[t * E_ + e0];
        for (int e = 0; e < E_; ++e) {
            float he = gelu_exact(fmaf(x, W1[t * E_ + e], b1[t * E_ + e]));
            float4 w = *(const float4*)&W2[((size_t)t * E_ + e) * E_ + e0];
            acc.x = fmaf(he, w.x, acc.x);
            acc.y = fmaf(he, w.y, acc.y);
            acc.z = fmaf(he, w.z, acc.z);
            acc.w = fmaf(he, w.w, acc.w);
        }
        v = acc;
    } else {
        int q = t - P_;
        int idx = x_cat[b * Q_ + q];
        v = *(const float4*)&emb[((size_t)q * V_ + idx) * E_ + e0];
    }
    ln_store(v, lane, e0, row, gamma, beta, out);
}

extern "C" void kernel_launch(void* const* d_in, const int* in_sizes, int n_in,
                              void* d_out, int out_size, void* d_ws, size_t ws_size,
                              hipStream_t stream) {
    const float* x_num = (const float*)d_in[0];
    const int*   x_cat = (const int*)d_in[1];
    const float* W1    = (const float*)d_in[2];
    const float* b1    = (const float*)d_in[3];
    const float* W2    = (const float*)d_in[4];
    const float* b2    = (const float*)d_in[5];
    const float* emb   = (const float*)d_in[6];
    const float* gamma = (const float*)d_in[7];
    const float* beta  = (const float*)d_in[8];
    float* out = (float*)d_out;

    size_t tbl_bytes = (size_t)P_ * NK_ * E_ * sizeof(float);
    int nrow_blocks = (B_ * TOK_ + 3) / 4;

    if (ws_size >= tbl_bytes) {
        float* Tbl = (float*)d_ws;
        dim3 g1(P_, (NK_ + KT_ - 1) / KT_);
        build_table<<<g1, 256, 0, stream>>>(W1, b1, W2, b2, Tbl);
        fuse_ln<<<nrow_blocks, 256, 0, stream>>>(Tbl, x_num, x_cat, emb, gamma, beta, out);
    } else {
        fuse_exact<<<nrow_blocks, 256, 0, stream>>>(x_num, x_cat, W1, b1, W2, b2,
                                                    emb, gamma, beta, out);
    }
}

// Round 2
// 107.280 us; speedup vs baseline: 1.0570x; 1.0570x over previous
//
#include <hip/hip_runtime.h>
#include <hip/hip_bf16.h>
#include <math.h>

#define B_ 8192
#define P_ 24
#define Q_ 12
#define E_ 256
#define V_ 1000
#define TOK_ 36
#define NK_ 129      // knots
#define NI_ 128      // intervals
#define KT_ 16       // knots per build block
#define X0_ (-6.0f)
#define DX_ (12.0f / 128.0f)
#define INVDX_ (128.0f / 12.0f)
#define LN_EPS_ 1e-5f

__device__ __forceinline__ float gelu_exact(float u) {
    return 0.5f * u * (1.0f + erff(u * 0.70710678118654752f));
}

// Build table T[p][k][f] = F_p(x_k)[f] = sum_e gelu(x_k*W1[p,e]+b1[p,e]) * W2[p,e,f] + b2[p,f]
__global__ __launch_bounds__(256) void build_table(
        const float* __restrict__ W1, const float* __restrict__ b1,
        const float* __restrict__ W2, const float* __restrict__ b2,
        float* __restrict__ T) {
    int p = blockIdx.x;
    int k0 = blockIdx.y * KT_;
    int f = threadIdx.x;

    __shared__ float h[KT_][E_ + 4];

    float w = W1[p * E_ + f];
    float b1v = b1[p * E_ + f];
    #pragma unroll
    for (int k = 0; k < KT_; ++k) {
        float x = X0_ + (float)(k0 + k) * DX_;
        h[k][f] = gelu_exact(fmaf(x, w, b1v));
    }
    __syncthreads();

    float acc[KT_];
    float b2v = b2[p * E_ + f];
    #pragma unroll
    for (int k = 0; k < KT_; ++k) acc[k] = b2v;

    const float* W2p = W2 + (size_t)p * E_ * E_ + f;
    for (int e = 0; e < E_; e += 4) {
        float w0 = W2p[(size_t)(e + 0) * E_];
        float w1 = W2p[(size_t)(e + 1) * E_];
        float w2v = W2p[(size_t)(e + 2) * E_];
        float w3 = W2p[(size_t)(e + 3) * E_];
        #pragma unroll
        for (int k = 0; k < KT_; ++k) {
            float4 hv = *(const float4*)&h[k][e];
            acc[k] = fmaf(hv.x, w0, acc[k]);
            acc[k] = fmaf(hv.y, w1, acc[k]);
            acc[k] = fmaf(hv.z, w2v, acc[k]);
            acc[k] = fmaf(hv.w, w3, acc[k]);
        }
    }
    #pragma unroll
    for (int k = 0; k < KT_; ++k) {
        int kk = k0 + k;
        if (kk < NK_) T[((size_t)p * NK_ + kk) * E_ + f] = acc[k];
    }
}

// LayerNorm one 256-elem row held as float4/lane across a 64-lane wave, then store.
__device__ __forceinline__ void ln_store(float4 v, float4 g, float4 bt, int e0, int row,
                                         float* __restrict__ out) {
    float s1 = v.x + v.y + v.z + v.w;
    #pragma unroll
    for (int m = 1; m < 64; m <<= 1) s1 += __shfl_xor(s1, m, 64);
    float mean = s1 * (1.0f / (float)E_);
    float dx = v.x - mean, dy = v.y - mean, dz = v.z - mean, dw = v.w - mean;
    float s2 = dx * dx + dy * dy + dz * dz + dw * dw;
    #pragma unroll
    for (int m = 1; m < 64; m <<= 1) s2 += __shfl_xor(s2, m, 64);
    float rstd = rsqrtf(s2 * (1.0f / (float)E_) + LN_EPS_);
    float4 o;
    o.x = fmaf(dx * rstd, g.x, bt.x);
    o.y = fmaf(dy * rstd, g.y, bt.y);
    o.z = fmaf(dz * rstd, g.z, bt.z);
    o.w = fmaf(dw * rstd, g.w, bt.w);
    *(float4*)&out[(size_t)row * E_ + e0] = o;
}

// Main fused kernel: 4 rows per wave (batched independent gathers), 4 waves per block.
// TOK_=36 is divisible by 4, so each aligned 4-row group is within one batch elem
// and is purely numeric (t0<24) or purely categorical (t0>=24).
__global__ __launch_bounds__(256) void fuse_ln4(
        const float* __restrict__ T,
        const float* __restrict__ x_num, const int* __restrict__ x_cat,
        const float* __restrict__ emb,
        const float* __restrict__ gamma, const float* __restrict__ beta,
        float* __restrict__ out) {
    int wv = threadIdx.x >> 6;
    int lane = threadIdx.x & 63;
    int wid = blockIdx.x * 4 + wv;
    int base = wid * 4;
    if (base >= B_ * TOK_) return;
    int b = base / TOK_;
    int t0 = base - b * TOK_;          // multiple of 4
    int e0 = lane * 4;

    float4 g = *(const float4*)&gamma[e0];
    float4 bt = *(const float4*)&beta[e0];

    float4 v[4];
    if (t0 < P_) {
        float4 x4 = *(const float4*)&x_num[b * P_ + t0];   // 16B-aligned (b*24+t0 % 4 == 0)
        float xs[4] = {x4.x, x4.y, x4.z, x4.w};
        const float* bases[4];
        float tts[4];
        #pragma unroll
        for (int j = 0; j < 4; ++j) {
            float s = (xs[j] - X0_) * INVDX_;
            float fi = floorf(s);
            fi = fminf(fmaxf(fi, 0.0f), (float)(NI_ - 1));
            tts[j] = s - fi;           // unclamped -> linear extrapolation out of range
            bases[j] = T + ((size_t)(t0 + j) * NK_ + (int)fi) * E_ + e0;
        }
        float4 a[4], c[4];
        #pragma unroll
        for (int j = 0; j < 4; ++j) {  // 8 independent loads in flight
            a[j] = *(const float4*)bases[j];
            c[j] = *(const float4*)(bases[j] + E_);
        }
        #pragma unroll
        for (int j = 0; j < 4; ++j) {
            v[j].x = fmaf(tts[j], c[j].x - a[j].x, a[j].x);
            v[j].y = fmaf(tts[j], c[j].y - a[j].y, a[j].y);
            v[j].z = fmaf(tts[j], c[j].z - a[j].z, a[j].z);
            v[j].w = fmaf(tts[j], c[j].w - a[j].w, a[j].w);
        }
    } else {
        int q0 = t0 - P_;              // 0, 4, or 8
        int4 id4 = *(const int4*)&x_cat[b * Q_ + q0];       // 16B-aligned (b*12+q0 % 4 == 0)
        int ids[4] = {id4.x, id4.y, id4.z, id4.w};
        #pragma unroll
        for (int j = 0; j < 4; ++j)    // 4 independent gathers in flight
            v[j] = *(const float4*)&emb[((size_t)(q0 + j) * V_ + ids[j]) * E_ + e0];
    }
    #pragma unroll
    for (int j = 0; j < 4; ++j) ln_store(v[j], g, bt, e0, base + j, out);
}

// Exact fallback (no workspace): direct per-row matvec. Slow but correct.
__global__ __launch_bounds__(256) void fuse_exact(
        const float* __restrict__ x_num, const int* __restrict__ x_cat,
        const float* __restrict__ W1, const float* __restrict__ b1,
        const float* __restrict__ W2, const float* __restrict__ b2,
        const float* __restrict__ emb,
        const float* __restrict__ gamma, const float* __restrict__ beta,
        float* __restrict__ out) {
    int wv = threadIdx.x >> 6;
    int lane = threadIdx.x & 63;
    int row = blockIdx.x * 4 + wv;
    if (row >= B_ * TOK_) return;
    int b = row / TOK_;
    int t = row - b * TOK_;
    int e0 = lane * 4;
    float4 g = *(const float4*)&gamma[e0];
    float4 bt = *(const float4*)&beta[e0];
    float4 v;
    if (t < P_) {
        float x = x_num[b * P_ + t];
        float4 acc = *(const float4*)&b2[t * E_ + e0];
        for (int e = 0; e < E_; ++e) {
            float he = gelu_exact(fmaf(x, W1[t * E_ + e], b1[t * E_ + e]));
            float4 w = *(const float4*)&W2[((size_t)t * E_ + e) * E_ + e0];
            acc.x = fmaf(he, w.x, acc.x);
            acc.y = fmaf(he, w.y, acc.y);
            acc.z = fmaf(he, w.z, acc.z);
            acc.w = fmaf(he, w.w, acc.w);
        }
        v = acc;
    } else {
        int q = t - P_;
        int idx = x_cat[b * Q_ + q];
        v = *(const float4*)&emb[((size_t)q * V_ + idx) * E_ + e0];
    }
    ln_store(v, g, bt, e0, row, out);
}

extern "C" void kernel_launch(void* const* d_in, const int* in_sizes, int n_in,
                              void* d_out, int out_size, void* d_ws, size_t ws_size,
                              hipStream_t stream) {
    const float* x_num = (const float*)d_in[0];
    const int*   x_cat = (const int*)d_in[1];
    const float* W1    = (const float*)d_in[2];
    const float* b1    = (const float*)d_in[3];
    const float* W2    = (const float*)d_in[4];
    const float* b2    = (const float*)d_in[5];
    const float* emb   = (const float*)d_in[6];
    const float* gamma = (const float*)d_in[7];
    const float* beta  = (const float*)d_in[8];
    float* out = (float*)d_out;

    size_t tbl_bytes = (size_t)P_ * NK_ * E_ * sizeof(float);

    if (ws_size >= tbl_bytes) {
        float* Tbl = (float*)d_ws;
        dim3 g1(P_, (NK_ + KT_ - 1) / KT_);
        build_table<<<g1, 256, 0, stream>>>(W1, b1, W2, b2, Tbl);
        int nwaves = (B_ * TOK_) / 4;          // 4 rows per wave
        int nblocks = nwaves / 4;              // 4 waves per block
        fuse_ln4<<<nblocks, 256, 0, stream>>>(Tbl, x_num, x_cat, emb, gamma, beta, out);
    } else {
        int nrow_blocks = (B_ * TOK_ + 3) / 4;
        fuse_exact<<<nrow_blocks, 256, 0, stream>>>(x_num, x_cat, W1, b1, W2, b2,
                                                    emb, gamma, beta, out);
    }
}

// Round 4
// 93.700 us; speedup vs baseline: 1.2102x; 1.1449x over previous
//
#include <hip/hip_runtime.h>
#include <hip/hip_bf16.h>
#include <math.h>

#define B_ 8192
#define P_ 24
#define Q_ 12
#define E_ 256
#define V_ 1000
#define TOK_ 36
#define NK_ 129      // knots
#define NI_ 128      // intervals
#define KT_ 16       // knots per build block
#define X0_ (-6.0f)
#define DX_ (12.0f / 128.0f)
#define INVDX_ (128.0f / 12.0f)
#define LN_EPS_ 1e-5f

typedef float vfloat4 __attribute__((ext_vector_type(4)));  // clang-native for nontemporal builtin

__device__ __forceinline__ float gelu_exact(float u) {
    return 0.5f * u * (1.0f + erff(u * 0.70710678118654752f));
}

// Build table T[p][k][f] = F_p(x_k)[f] = sum_e gelu(x_k*W1[p,e]+b1[p,e]) * W2[p,e,f] + b2[p,f]
__global__ __launch_bounds__(256) void build_table(
        const float* __restrict__ W1, const float* __restrict__ b1,
        const float* __restrict__ W2, const float* __restrict__ b2,
        float* __restrict__ T) {
    int p = blockIdx.x;
    int k0 = blockIdx.y * KT_;
    int f = threadIdx.x;

    __shared__ float h[KT_][E_ + 4];

    float w = W1[p * E_ + f];
    float b1v = b1[p * E_ + f];
    #pragma unroll
    for (int k = 0; k < KT_; ++k) {
        float x = X0_ + (float)(k0 + k) * DX_;
        h[k][f] = gelu_exact(fmaf(x, w, b1v));
    }
    __syncthreads();

    float acc[KT_];
    float b2v = b2[p * E_ + f];
    #pragma unroll
    for (int k = 0; k < KT_; ++k) acc[k] = b2v;

    const float* W2p = W2 + (size_t)p * E_ * E_ + f;
    for (int e = 0; e < E_; e += 4) {
        float w0 = W2p[(size_t)(e + 0) * E_];
        float w1 = W2p[(size_t)(e + 1) * E_];
        float w2v = W2p[(size_t)(e + 2) * E_];
        float w3 = W2p[(size_t)(e + 3) * E_];
        #pragma unroll
        for (int k = 0; k < KT_; ++k) {
            float4 hv = *(const float4*)&h[k][e];
            acc[k] = fmaf(hv.x, w0, acc[k]);
            acc[k] = fmaf(hv.y, w1, acc[k]);
            acc[k] = fmaf(hv.z, w2v, acc[k]);
            acc[k] = fmaf(hv.w, w3, acc[k]);
        }
    }
    #pragma unroll
    for (int k = 0; k < KT_; ++k) {
        int kk = k0 + k;
        if (kk < NK_) T[((size_t)p * NK_ + kk) * E_ + f] = acc[k];
    }
}

// LayerNorm one 256-elem row (float4/lane across 64 lanes), nontemporal store.
__device__ __forceinline__ void ln_store(float4 v, float4 g, float4 bt, int e0, int row,
                                         float* __restrict__ out) {
    float s1 = v.x + v.y + v.z + v.w;
    #pragma unroll
    for (int m = 1; m < 64; m <<= 1) s1 += __shfl_xor(s1, m, 64);
    float mean = s1 * (1.0f / (float)E_);
    float dx = v.x - mean, dy = v.y - mean, dz = v.z - mean, dw = v.w - mean;
    float s2 = dx * dx + dy * dy + dz * dz + dw * dw;
    #pragma unroll
    for (int m = 1; m < 64; m <<= 1) s2 += __shfl_xor(s2, m, 64);
    float rstd = rsqrtf(s2 * (1.0f / (float)E_) + LN_EPS_);
    vfloat4 o;
    o.x = fmaf(dx * rstd, g.x, bt.x);
    o.y = fmaf(dy * rstd, g.y, bt.y);
    o.z = fmaf(dz * rstd, g.z, bt.z);
    o.w = fmaf(dw * rstd, g.w, bt.w);
    // Output is write-once, never re-read: bypass L2 so table/emb stay resident.
    __builtin_nontemporal_store(o, (vfloat4*)&out[(size_t)row * E_ + e0]);
}

// Main fused kernel, token-group-major grid:
//   blockIdx.x = tgrp * (B/4) + bblk;  wave wv handles b = bblk*4+wv, rows t0..t0+3
// where t0 = tgrp*4. All CUs work on the same 4 tokens at any instant, so the
// active emb slab (4 q's = 4 MB) / table slab (4 p's = 0.5 MB) is L2-resident.
__global__ __launch_bounds__(256) void fuse_ln4(
        const float* __restrict__ T,
        const float* __restrict__ x_num, const int* __restrict__ x_cat,
        const float* __restrict__ emb,
        const float* __restrict__ gamma, const float* __restrict__ beta,
        float* __restrict__ out) {
    int wv = threadIdx.x >> 6;
    int lane = threadIdx.x & 63;
    int tgrp = blockIdx.x / (B_ / 4);
    int bblk = blockIdx.x - tgrp * (B_ / 4);
    int b = bblk * 4 + wv;
    int t0 = tgrp * 4;
    int e0 = lane * 4;

    float4 g = *(const float4*)&gamma[e0];
    float4 bt = *(const float4*)&beta[e0];

    float4 v[4];
    if (t0 < P_) {
        float4 x4 = *(const float4*)&x_num[b * P_ + t0];   // 16B-aligned
        float xs[4] = {x4.x, x4.y, x4.z, x4.w};
        const float* bases[4];
        float tts[4];
        #pragma unroll
        for (int j = 0; j < 4; ++j) {
            float s = (xs[j] - X0_) * INVDX_;
            float fi = floorf(s);
            fi = fminf(fmaxf(fi, 0.0f), (float)(NI_ - 1));
            tts[j] = s - fi;           // unclamped -> linear extrapolation out of range
            bases[j] = T + ((size_t)(t0 + j) * NK_ + (int)fi) * E_ + e0;
        }
        float4 a[4], c[4];
        #pragma unroll
        for (int j = 0; j < 4; ++j) {  // 8 independent loads in flight
            a[j] = *(const float4*)bases[j];
            c[j] = *(const float4*)(bases[j] + E_);
        }
        #pragma unroll
        for (int j = 0; j < 4; ++j) {
            v[j].x = fmaf(tts[j], c[j].x - a[j].x, a[j].x);
            v[j].y = fmaf(tts[j], c[j].y - a[j].y, a[j].y);
            v[j].z = fmaf(tts[j], c[j].z - a[j].z, a[j].z);
            v[j].w = fmaf(tts[j], c[j].w - a[j].w, a[j].w);
        }
    } else {
        int q0 = t0 - P_;              // 0, 4, or 8
        int4 id4 = *(const int4*)&x_cat[b * Q_ + q0];       // 16B-aligned
        int ids[4] = {id4.x, id4.y, id4.z, id4.w};
        #pragma unroll
        for (int j = 0; j < 4; ++j)    // 4 independent gathers in flight
            v[j] = *(const float4*)&emb[((size_t)(q0 + j) * V_ + ids[j]) * E_ + e0];
    }
    int base_row = b * TOK_ + t0;
    #pragma unroll
    for (int j = 0; j < 4; ++j) ln_store(v[j], g, bt, e0, base_row + j, out);
}

// Exact fallback (no workspace): direct per-row matvec. Slow but correct.
__global__ __launch_bounds__(256) void fuse_exact(
        const float* __restrict__ x_num, const int* __restrict__ x_cat,
        const float* __restrict__ W1, const float* __restrict__ b1,
        const float* __restrict__ W2, const float* __restrict__ b2,
        const float* __restrict__ emb,
        const float* __restrict__ gamma, const float* __restrict__ beta,
        float* __restrict__ out) {
    int wv = threadIdx.x >> 6;
    int lane = threadIdx.x & 63;
    int row = blockIdx.x * 4 + wv;
    if (row >= B_ * TOK_) return;
    int b = row / TOK_;
    int t = row - b * TOK_;
    int e0 = lane * 4;
    float4 g = *(const float4*)&gamma[e0];
    float4 bt = *(const float4*)&beta[e0];
    float4 v;
    if (t < P_) {
        float x = x_num[b * P_ + t];
        float4 acc = *(const float4*)&b2[t * E_ + e0];
        for (int e = 0; e < E_; ++e) {
            float he = gelu_exact(fmaf(x, W1[t * E_ + e], b1[t * E_ + e]));
            float4 w = *(const float4*)&W2[((size_t)t * E_ + e) * E_ + e0];
            acc.x = fmaf(he, w.x, acc.x);
            acc.y = fmaf(he, w.y, acc.y);
            acc.z = fmaf(he, w.z, acc.z);
            acc.w = fmaf(he, w.w, acc.w);
        }
        v = acc;
    } else {
        int q = t - P_;
        int idx = x_cat[b * Q_ + q];
        v = *(const float4*)&emb[((size_t)q * V_ + idx) * E_ + e0];
    }
    ln_store(v, g, bt, e0, row, out);
}

extern "C" void kernel_launch(void* const* d_in, const int* in_sizes, int n_in,
                              void* d_out, int out_size, void* d_ws, size_t ws_size,
                              hipStream_t stream) {
    const float* x_num = (const float*)d_in[0];
    const int*   x_cat = (const int*)d_in[1];
    const float* W1    = (const float*)d_in[2];
    const float* b1    = (const float*)d_in[3];
    const float* W2    = (const float*)d_in[4];
    const float* b2    = (const float*)d_in[5];
    const float* emb   = (const float*)d_in[6];
    const float* gamma = (const float*)d_in[7];
    const float* beta  = (const float*)d_in[8];
    float* out = (float*)d_out;

    size_t tbl_bytes = (size_t)P_ * NK_ * E_ * sizeof(float);

    if (ws_size >= tbl_bytes) {
        float* Tbl = (float*)d_ws;
        dim3 g1(P_, (NK_ + KT_ - 1) / KT_);
        build_table<<<g1, 256, 0, stream>>>(W1, b1, W2, b2, Tbl);
        int nblocks = (TOK_ / 4) * (B_ / 4);   // 9 token-groups x 2048 b-chunks
        fuse_ln4<<<nblocks, 256, 0, stream>>>(Tbl, x_num, x_cat, emb, gamma, beta, out);
    } else {
        int nrow_blocks = (B_ * TOK_ + 3) / 4;
        fuse_exact<<<nrow_blocks, 256, 0, stream>>>(x_num, x_cat, W1, b1, W2, b2,
                                                    emb, gamma, beta, out);
    }
}

// Round 5
// 79.860 us; speedup vs baseline: 1.4200x; 1.1733x over previous
//
#include <hip/hip_runtime.h>
#include <hip/hip_bf16.h>
#include <math.h>

#define B_ 8192
#define P_ 24
#define Q_ 12
#define E_ 256
#define V_ 1000
#define TOK_ 36
#define NK_ 129      // knots
#define NI_ 128      // intervals
#define KT_ 16       // knots per build block
#define NKBLK_ 9     // ceil(129/16)
#define NBUILD_BLK_ (P_ * NKBLK_)   // 216
#define X0_ (-6.0f)
#define DX_ (12.0f / 128.0f)
#define INVDX_ (128.0f / 12.0f)
#define LN_EPS_ 1e-5f

typedef float vfloat4 __attribute__((ext_vector_type(4)));

__device__ __forceinline__ float gelu_exact(float u) {
    return 0.5f * u * (1.0f + erff(u * 0.70710678118654752f));
}

// LayerNorm one 256-elem row (float4/lane across 64 lanes), nontemporal store.
__device__ __forceinline__ void ln_store(float4 v, float4 g, float4 bt, int e0, int row,
                                         float* __restrict__ out) {
    float s1 = v.x + v.y + v.z + v.w;
    #pragma unroll
    for (int m = 1; m < 64; m <<= 1) s1 += __shfl_xor(s1, m, 64);
    float mean = s1 * (1.0f / (float)E_);
    float dx = v.x - mean, dy = v.y - mean, dz = v.z - mean, dw = v.w - mean;
    float s2 = dx * dx + dy * dy + dz * dz + dw * dw;
    #pragma unroll
    for (int m = 1; m < 64; m <<= 1) s2 += __shfl_xor(s2, m, 64);
    float rstd = rsqrtf(s2 * (1.0f / (float)E_) + LN_EPS_);
    vfloat4 o;
    o.x = fmaf(dx * rstd, g.x, bt.x);
    o.y = fmaf(dy * rstd, g.y, bt.y);
    o.z = fmaf(dz * rstd, g.z, bt.z);
    o.w = fmaf(dw * rstd, g.w, bt.w);
    // out is write-once, never re-read: bypass L2 so table/emb stay resident.
    __builtin_nontemporal_store(o, (vfloat4*)&out[(size_t)row * E_ + e0]);
}

// Kernel 1: blocks [0,216) build the interpolation table T[p][k][f];
// blocks [216, 216+6144) process ALL categorical tokens (independent of T).
// The cat waves provide TLP that hides the build blocks' load latency.
__global__ __launch_bounds__(256) void build_and_cat(
        const float* __restrict__ W1, const float* __restrict__ b1,
        const float* __restrict__ W2, const float* __restrict__ b2,
        const int* __restrict__ x_cat, const float* __restrict__ emb,
        const float* __restrict__ gamma, const float* __restrict__ beta,
        float* __restrict__ T, float* __restrict__ out) {
    __shared__ float h[KT_][E_ + 4];

    if (blockIdx.x < NBUILD_BLK_) {
        // ---- table build ----
        int p = blockIdx.x / NKBLK_;
        int k0 = (blockIdx.x - p * NKBLK_) * KT_;
        int f = threadIdx.x;

        float w = W1[p * E_ + f];
        float b1v = b1[p * E_ + f];
        #pragma unroll
        for (int k = 0; k < KT_; ++k) {
            float x = X0_ + (float)(k0 + k) * DX_;
            h[k][f] = gelu_exact(fmaf(x, w, b1v));
        }
        __syncthreads();

        float acc[KT_];
        float b2v = b2[p * E_ + f];
        #pragma unroll
        for (int k = 0; k < KT_; ++k) acc[k] = b2v;

        const float* W2p = W2 + (size_t)p * E_ * E_ + f;
        for (int e = 0; e < E_; e += 4) {
            float w0 = W2p[(size_t)(e + 0) * E_];
            float w1 = W2p[(size_t)(e + 1) * E_];
            float w2v = W2p[(size_t)(e + 2) * E_];
            float w3 = W2p[(size_t)(e + 3) * E_];
            #pragma unroll
            for (int k = 0; k < KT_; ++k) {
                float4 hv = *(const float4*)&h[k][e];
                acc[k] = fmaf(hv.x, w0, acc[k]);
                acc[k] = fmaf(hv.y, w1, acc[k]);
                acc[k] = fmaf(hv.z, w2v, acc[k]);
                acc[k] = fmaf(hv.w, w3, acc[k]);
            }
        }
        #pragma unroll
        for (int k = 0; k < KT_; ++k) {
            int kk = k0 + k;
            if (kk < NK_) T[((size_t)p * NK_ + kk) * E_ + f] = acc[k];
        }
    } else {
        // ---- categorical tokens: 4 rows/wave, 16 rows/block, row-major ----
        int cbid = blockIdx.x - NBUILD_BLK_;
        int wv = threadIdx.x >> 6;
        int lane = threadIdx.x & 63;
        int r = cbid * 16 + wv * 4;            // cat-row index in [0, B*Q)
        int b = r / Q_;
        int q0 = r - b * Q_;                   // in {0,4,8}
        int e0 = lane * 4;

        float4 g = *(const float4*)&gamma[e0];
        float4 bt = *(const float4*)&beta[e0];

        int4 id4 = *(const int4*)&x_cat[b * Q_ + q0];   // 16B-aligned
        int ids[4] = {id4.x, id4.y, id4.z, id4.w};
        float4 v[4];
        #pragma unroll
        for (int j = 0; j < 4; ++j)
            v[j] = *(const float4*)&emb[((size_t)(q0 + j) * V_ + ids[j]) * E_ + e0];

        int base_row = b * TOK_ + P_ + q0;
        #pragma unroll
        for (int j = 0; j < 4; ++j) ln_store(v[j], g, bt, e0, base_row + j, out);
    }
}

// Kernel 2: numeric tokens via table interpolation. Table is L2-hot (3.2 MB/XCD).
__global__ __launch_bounds__(256) void fuse_num(
        const float* __restrict__ T,
        const float* __restrict__ x_num,
        const float* __restrict__ gamma, const float* __restrict__ beta,
        float* __restrict__ out) {
    int wv = threadIdx.x >> 6;
    int lane = threadIdx.x & 63;
    int r = blockIdx.x * 16 + wv * 4;          // num-row index in [0, B*P)
    int b = r / P_;
    int t0 = r - b * P_;                       // multiple of 4
    int e0 = lane * 4;

    float4 g = *(const float4*)&gamma[e0];
    float4 bt = *(const float4*)&beta[e0];

    float4 x4 = *(const float4*)&x_num[b * P_ + t0];   // 16B-aligned
    float xs[4] = {x4.x, x4.y, x4.z, x4.w};
    const float* bases[4];
    float tts[4];
    #pragma unroll
    for (int j = 0; j < 4; ++j) {
        float s = (xs[j] - X0_) * INVDX_;
        float fi = floorf(s);
        fi = fminf(fmaxf(fi, 0.0f), (float)(NI_ - 1));
        tts[j] = s - fi;               // unclamped -> linear extrapolation out of range
        bases[j] = T + ((size_t)(t0 + j) * NK_ + (int)fi) * E_ + e0;
    }
    float4 a[4], c[4];
    #pragma unroll
    for (int j = 0; j < 4; ++j) {      // 8 independent loads in flight
        a[j] = *(const float4*)bases[j];
        c[j] = *(const float4*)(bases[j] + E_);
    }
    float4 v[4];
    #pragma unroll
    for (int j = 0; j < 4; ++j) {
        v[j].x = fmaf(tts[j], c[j].x - a[j].x, a[j].x);
        v[j].y = fmaf(tts[j], c[j].y - a[j].y, a[j].y);
        v[j].z = fmaf(tts[j], c[j].z - a[j].z, a[j].z);
        v[j].w = fmaf(tts[j], c[j].w - a[j].w, a[j].w);
    }
    int base_row = b * TOK_ + t0;
    #pragma unroll
    for (int j = 0; j < 4; ++j) ln_store(v[j], g, bt, e0, base_row + j, out);
}

// Exact fallback (no workspace): direct per-row matvec. Slow but correct.
__global__ __launch_bounds__(256) void fuse_exact(
        const float* __restrict__ x_num, const int* __restrict__ x_cat,
        const float* __restrict__ W1, const float* __restrict__ b1,
        const float* __restrict__ W2, const float* __restrict__ b2,
        const float* __restrict__ emb,
        const float* __restrict__ gamma, const float* __restrict__ beta,
        float* __restrict__ out) {
    int wv = threadIdx.x >> 6;
    int lane = threadIdx.x & 63;
    int row = blockIdx.x * 4 + wv;
    if (row >= B_ * TOK_) return;
    int b = row / TOK_;
    int t = row - b * TOK_;
    int e0 = lane * 4;
    float4 g = *(const float4*)&gamma[e0];
    float4 bt = *(const float4*)&beta[e0];
    float4 v;
    if (t < P_) {
        float x = x_num[b * P_ + t];
        float4 acc = *(const float4*)&b2[t * E_ + e0];
        for (int e = 0; e < E_; ++e) {
            float he = gelu_exact(fmaf(x, W1[t * E_ + e], b1[t * E_ + e]));
            float4 w = *(const float4*)&W2[((size_t)t * E_ + e) * E_ + e0];
            acc.x = fmaf(he, w.x, acc.x);
            acc.y = fmaf(he, w.y, acc.y);
            acc.z = fmaf(he, w.z, acc.z);
            acc.w = fmaf(he, w.w, acc.w);
        }
        v = acc;
    } else {
        int q = t - P_;
        int idx = x_cat[b * Q_ + q];
        v = *(const float4*)&emb[((size_t)q * V_ + idx) * E_ + e0];
    }
    ln_store(v, g, bt, e0, row, out);
}

extern "C" void kernel_launch(void* const* d_in, const int* in_sizes, int n_in,
                              void* d_out, int out_size, void* d_ws, size_t ws_size,
                              hipStream_t stream) {
    const float* x_num = (const float*)d_in[0];
    const int*   x_cat = (const int*)d_in[1];
    const float* W1    = (const float*)d_in[2];
    const float* b1    = (const float*)d_in[3];
    const float* W2    = (const float*)d_in[4];
    const float* b2    = (const float*)d_in[5];
    const float* emb   = (const float*)d_in[6];
    const float* gamma = (const float*)d_in[7];
    const float* beta  = (const float*)d_in[8];
    float* out = (float*)d_out;

    size_t tbl_bytes = (size_t)P_ * NK_ * E_ * sizeof(float);

    if (ws_size >= tbl_bytes) {
        float* Tbl = (float*)d_ws;
        int ncat_blocks = (B_ * Q_) / 16;          // 6144 (4 rows/wave, 4 waves/block)
        build_and_cat<<<NBUILD_BLK_ + ncat_blocks, 256, 0, stream>>>(
            W1, b1, W2, b2, x_cat, emb, gamma, beta, Tbl, out);
        int nnum_blocks = (B_ * P_) / 16;          // 12288
        fuse_num<<<nnum_blocks, 256, 0, stream>>>(Tbl, x_num, gamma, beta, out);
    } else {
        int nrow_blocks = (B_ * TOK_ + 3) / 4;
        fuse_exact<<<nrow_blocks, 256, 0, stream>>>(x_num, x_cat, W1, b1, W2, b2,
                                                    emb, gamma, beta, out);
    }
}